// Round 17
// baseline (597.224 us; speedup 1.0000x reference)
//
#include <hip/hip_runtime.h>
#include <hip/hip_bf16.h>
#include <math.h>

#define T_STEPS 16

typedef __attribute__((ext_vector_type(8))) short bf16x8;
typedef __attribute__((ext_vector_type(16))) float f32x16;
typedef __attribute__((ext_vector_type(2))) float f32x2;

// ---- prep (merged): w [co128][ci128][tap9] f32 -> wp [s3][tap9][kc16][co128][e8] bf16
__global__ __launch_bounds__(256) void prep_w3_kernel(
    const float* __restrict__ w2, const float* __restrict__ w3,
    const float* __restrict__ w4, __hip_bfloat16* __restrict__ wp2,
    __hip_bfloat16* __restrict__ wp3, __hip_bfloat16* __restrict__ wp4) {
  const float* w = blockIdx.y == 0 ? w2 : (blockIdx.y == 1 ? w3 : w4);
  __hip_bfloat16* wp = blockIdx.y == 0 ? wp2 : (blockIdx.y == 1 ? wp3 : wp4);
  int idx = blockIdx.x * 256 + threadIdx.x;
  if (idx >= 147456) return;
  int co = idx / 1152, rem = idx - co * 1152;
  int ci = rem / 9, tap = rem - ci * 9;
  float x = w[idx];
  float h = (float)__float2bfloat16(x);
  float r1 = x - h;
  float m = (float)__float2bfloat16(r1);
  float r2 = r1 - m;
  size_t base = (((size_t)tap * 16 + (ci >> 3)) * 128 + co) * 8 + (ci & 7);
  const size_t SSZ = 147456;
  wp[base] = __float2bfloat16(h);
  wp[SSZ + base] = __float2bfloat16(m);
  wp[2 * SSZ + base] = __float2bfloat16(r2);
}

// ---- pad_x: x [plane 128][128][128] -> xp [plane][130][132] zero-padded -----
__global__ __launch_bounds__(192) void pad_x_kernel(const float* __restrict__ x,
                                                    float* __restrict__ xp) {
  const int plane = blockIdx.x;
  const int row = blockIdx.y;
  const int c = threadIdx.x;
  if (c < 132) {
    float v = 0.f;
    int gr = row - 1, gc = c - 1;
    if ((unsigned)gr < 128u && (unsigned)gc < 128u)
      v = x[(size_t)plane * 16384 + gr * 128 + gc];
    xp[((size_t)plane * 130 + row) * 132 + c] = v;
  }
}

// ---- layer 1: conv(2->128)+BN+LIF+pool, pk-fma, t+1 load prefetch -----------
__global__ __launch_bounds__(256) void layer1_kernel(
    const float* __restrict__ xp, const float* __restrict__ w,
    const float* __restrict__ gn, const float* __restrict__ bn,
    const float* __restrict__ mn, const float* __restrict__ vn,
    __hip_bfloat16* __restrict__ out, int coBase) {
  const int tid = threadIdx.x;
  const int tile = blockIdx.x;
  const int ty0 = (tile >> 2) * 32, tx0 = (tile & 3) * 32;
  const int co0 = coBase + blockIdx.y * 4;
  const int b = blockIdx.z;
  const int qx2 = (tid & 15) * 2;
  const int qy2 = (tid >> 4) * 2;
  const int yq = ty0 + qy2;
  const int xq = tx0 + qx2;

  float wreg[2][9][4];
#pragma unroll
  for (int j = 0; j < 4; ++j)
#pragma unroll
    for (int ci = 0; ci < 2; ++ci)
#pragma unroll
      for (int tap = 0; tap < 9; ++tap)
        wreg[ci][tap][j] = w[(co0 + j) * 18 + ci * 9 + tap];

  float scale[4], shift[4];
#pragma unroll
  for (int j = 0; j < 4; ++j) {
    float inv = gn[co0 + j] / sqrtf(vn[co0 + j] + 1e-5f);
    scale[j] = inv;
    shift[j] = bn[co0 + j] - mn[co0 + j] * inv;
  }

  float vm[4][4];
#pragma unroll
  for (int j = 0; j < 4; ++j)
#pragma unroll
    for (int p = 0; p < 4; ++p) vm[j][p] = 0.f;

  // prefetch t = 0 input tile
  float iv[2][4][4];
  {
    const float* xpt = xp + (size_t)(b * 2) * 17160;
#pragma unroll
    for (int ci = 0; ci < 2; ++ci)
#pragma unroll
      for (int r = 0; r < 4; ++r)
        *(float4*)&iv[ci][r][0] =
            *(const float4*)(xpt + (size_t)(ci * 130 + yq + r) * 132 + xq);
  }

  for (int t = 0; t < T_STEPS; ++t) {
    // issue next-t loads early; FMA compute below hides the latency
    float ivn[2][4][4];
    if (t + 1 < T_STEPS) {
      const float* xpn = xp + (size_t)(((t + 1) * 4 + b) * 2) * 17160;
#pragma unroll
      for (int ci = 0; ci < 2; ++ci)
#pragma unroll
        for (int r = 0; r < 4; ++r)
          *(float4*)&ivn[ci][r][0] =
              *(const float4*)(xpn + (size_t)(ci * 130 + yq + r) * 132 + xq);
    }

    f32x2 acc2[4][2];
#pragma unroll
    for (int j = 0; j < 4; ++j)
#pragma unroll
      for (int sy = 0; sy < 2; ++sy) acc2[j][sy] = (f32x2){0.f, 0.f};

#pragma unroll
    for (int ci = 0; ci < 2; ++ci)
#pragma unroll
      for (int tap = 0; tap < 9; ++tap) {
        const int dy = tap / 3, dx = tap - dy * 3;
#pragma unroll
        for (int sy = 0; sy < 2; ++sy) {
          f32x2 x2;
          x2[0] = iv[ci][sy + dy][dx];
          x2[1] = iv[ci][sy + dy][dx + 1];
#pragma unroll
          for (int j = 0; j < 4; ++j) {
            f32x2 w2 = {wreg[ci][tap][j], wreg[ci][tap][j]};
            acc2[j][sy] += w2 * x2;     // -> v_pk_fma_f32
          }
        }
      }

    const int py = (ty0 >> 1) + (tid >> 4);
    const int px = (tx0 >> 1) + (tid & 15);
    short4 pk;
    short* pks = (short*)&pk;
#pragma unroll
    for (int j = 0; j < 4; ++j) {
      float mx = -1e30f;
#pragma unroll
      for (int p = 0; p < 4; ++p) {
        float yv = acc2[j][p >> 1][p & 1] * scale[j] + shift[j];
        float nv = vm[j][p] + (yv - vm[j][p]) * 0.5f;
        mx = fmaxf(mx, nv);
        vm[j][p] = (nv >= 1.0f) ? 0.f : nv;
      }
      __hip_bfloat16 bv = __float2bfloat16(mx >= 1.0f ? 1.0f : 0.0f);
      pks[j] = *(short*)&bv;
    }
    *(short4*)(out + (((size_t)(t * 4 + b) * 64 + py) * 64 + px) * 128 + co0) = pk;

    if (t + 1 < T_STEPS) {
#pragma unroll
      for (int ci = 0; ci < 2; ++ci)
#pragma unroll
        for (int r = 0; r < 4; ++r)
#pragma unroll
          for (int c = 0; c < 4; ++c) iv[ci][r][c] = ivn[ci][r][c];
    }
  }
}

// ---- conv layers 2-3: 8x8 tile, TWO tb per block, tap unrolled, setprio -----
template <int S>
__global__ __launch_bounds__(256) void conv32p_kernel(
    const __hip_bfloat16* __restrict__ spk, const __hip_bfloat16* __restrict__ wp,
    float* __restrict__ pre, int tb_base) {
  constexpr int TILES_X = S / 8;
  const int tile = blockIdx.x;
  const int ty0 = (tile / TILES_X) * 8;
  const int tx0 = (tile % TILES_X) * 8;
  const int pair = blockIdx.z;
  const int tbl0 = pair * 2;
  const int tb0 = tb_base + tbl0;
  const int tid = threadIdx.x;
  const int lane = tid & 63;
  const int wv = tid >> 6;

  __shared__ uint4 At4[2][1600];

#pragma unroll
  for (int i = 0; i < 2; ++i) {
    const __hip_bfloat16* sp = spk + (size_t)(tb0 + i) * S * S * 128;
    for (int job = tid; job < 1600; job += 256) {
      int c8 = job & 15, si = job >> 4;
      int y = (si * 6554) >> 16;
      int xx = si - y * 10;
      int gy = ty0 - 1 + y, gx = tx0 - 1 + xx;
      uint4 v = make_uint4(0u, 0u, 0u, 0u);
      if ((unsigned)gy < (unsigned)S && (unsigned)gx < (unsigned)S)
        v = *(const uint4*)(sp + ((size_t)(gy * S + gx)) * 128 + c8 * 8);
      At4[i][(y * 10 + xx) * 16 + (c8 ^ (xx & 7))] = v;
    }
  }
  __syncthreads();

  const int l31 = lane & 31, hh = lane >> 5;
  const int co = wv * 32 + l31;
  const int ly = l31 >> 3, lx = lane & 7;

  f32x16 acc0[2], acc1[2];
#pragma unroll
  for (int m = 0; m < 2; ++m)
#pragma unroll
    for (int r = 0; r < 16; ++r) { acc0[m][r] = 0.f; acc1[m][r] = 0.f; }

  const short* wpb = (const short*)wp + (size_t)co * 8;

#pragma unroll
  for (int tap = 0; tap < 9; ++tap) {
    const int dy = tap / 3, dx = tap - dy * 3;
    const int xx = lx + dx;
    const int sx7 = xx & 7;
#pragma unroll
    for (int kk = 0; kk < 8; ++kk) {
      const int kc = kk * 2 + hh;
      bf16x8 a0[2], a1[2];
#pragma unroll
      for (int m = 0; m < 2; ++m) {
        const int slot = ((m * 4 + ly + dy) * 10 + xx) * 16 + (kc ^ sx7);
        a0[m] = *(const bf16x8*)(At4[0] + slot);
        a1[m] = *(const bf16x8*)(At4[1] + slot);
      }
#pragma unroll
      for (int s = 0; s < 3; ++s) {
        bf16x8 bfr = *(const bf16x8*)(wpb + ((size_t)(s * 9 + tap) * 16 + kc) * 1024);
        __builtin_amdgcn_s_setprio(1);
#pragma unroll
        for (int m = 0; m < 2; ++m)
          acc0[m] = __builtin_amdgcn_mfma_f32_32x32x16_bf16(a0[m], bfr, acc0[m], 0, 0, 0);
#pragma unroll
        for (int m = 0; m < 2; ++m)
          acc1[m] = __builtin_amdgcn_mfma_f32_32x32x16_bf16(a1[m], bfr, acc1[m], 0, 0, 0);
        __builtin_amdgcn_s_setprio(0);
      }
    }
  }

  float* po0 = pre + (size_t)tbl0 * S * S * 128 + co;
  float* po1 = pre + (size_t)(tbl0 + 1) * S * S * 128 + co;
#pragma unroll
  for (int m = 0; m < 2; ++m)
#pragma unroll
    for (int r = 0; r < 16; ++r) {
      int row = (r & 3) + 8 * (r >> 2) + 4 * hh;
      int p = m * 32 + row;
      size_t off = ((size_t)(ty0 + (p >> 3)) * S + tx0 + (p & 7)) * 128;
      po0[off] = acc0[m][r];
      po1[off] = acc1[m][r];
    }
}

// ---- conv layer 4: 8x8 tile, single tb, tap unrolled, setprio ---------------
template <int S>
__global__ __launch_bounds__(256) void conv32_kernel(
    const __hip_bfloat16* __restrict__ spk, const __hip_bfloat16* __restrict__ wp,
    float* __restrict__ pre, int t_base) {
  constexpr int TILES_X = S / 8;
  const int tile = blockIdx.x;
  const int ty0 = (tile / TILES_X) * 8;
  const int tx0 = (tile % TILES_X) * 8;
  const int tbl = blockIdx.z;
  const int tbg = t_base * 4 + tbl;
  const int tid = threadIdx.x;
  const int lane = tid & 63;
  const int wv = tid >> 6;

  __shared__ uint4 At4[1600];

  const __hip_bfloat16* sp = spk + (size_t)tbg * S * S * 128;
#pragma unroll
  for (int k = 0; k < 7; ++k) {
    int job = k * 256 + tid;
    if (job < 1600) {
      int c8 = job & 15, si = job >> 4;
      int y = (si * 6554) >> 16;
      int xx = si - y * 10;
      int gy = ty0 - 1 + y, gx = tx0 - 1 + xx;
      uint4 v = make_uint4(0u, 0u, 0u, 0u);
      if ((unsigned)gy < (unsigned)S && (unsigned)gx < (unsigned)S)
        v = *(const uint4*)(sp + ((size_t)(gy * S + gx)) * 128 + c8 * 8);
      At4[(y * 10 + xx) * 16 + (c8 ^ (xx & 7))] = v;
    }
  }
  __syncthreads();

  const int l31 = lane & 31, hh = lane >> 5;
  const int co = wv * 32 + l31;
  const int ly = l31 >> 3, lx = lane & 7;

  f32x16 acc[2];
#pragma unroll
  for (int m = 0; m < 2; ++m)
#pragma unroll
    for (int r = 0; r < 16; ++r) acc[m][r] = 0.f;

  const short* wpb = (const short*)wp + (size_t)co * 8;

#pragma unroll
  for (int tap = 0; tap < 9; ++tap) {
    const int dy = tap / 3, dx = tap - dy * 3;
    const int xx = lx + dx;
    const int sx7 = xx & 7;
#pragma unroll
    for (int kk = 0; kk < 8; ++kk) {
      const int kc = kk * 2 + hh;
      bf16x8 a[2];
#pragma unroll
      for (int m = 0; m < 2; ++m)
        a[m] = *(const bf16x8*)(At4 + ((m * 4 + ly + dy) * 10 + xx) * 16 + (kc ^ sx7));
#pragma unroll
      for (int s = 0; s < 3; ++s) {
        bf16x8 bfr = *(const bf16x8*)(wpb + ((size_t)(s * 9 + tap) * 16 + kc) * 1024);
        __builtin_amdgcn_s_setprio(1);
#pragma unroll
        for (int m = 0; m < 2; ++m)
          acc[m] = __builtin_amdgcn_mfma_f32_32x32x16_bf16(a[m], bfr, acc[m], 0, 0, 0);
        __builtin_amdgcn_s_setprio(0);
      }
    }
  }

  float* po = pre + (size_t)tbl * S * S * 128 + co;
#pragma unroll
  for (int m = 0; m < 2; ++m)
#pragma unroll
    for (int r = 0; r < 16; ++r) {
      int row = (r & 3) + 8 * (r >> 2) + 4 * hh;
      int p = m * 32 + row;
      po[((size_t)(ty0 + (p >> 3)) * S + tx0 + (p & 7)) * 128] = acc[m][r];
    }
}

// ---- BN + LIF + pool pass (layers 2-4) --------------------------------------
template <int S>
__global__ __launch_bounds__(256) void lif_pool_kernel(
    const float* __restrict__ pre, __hip_bfloat16* __restrict__ spk,
    float* __restrict__ vm, const float* __restrict__ gn,
    const float* __restrict__ bn, const float* __restrict__ mn,
    const float* __restrict__ vn, int t_base, int nt) {
  constexpr int OS = S / 2, NQ = OS * OS;
  const int tid = threadIdx.x;
  const int co = tid & 127;
  const int q = blockIdx.x * 2 + (tid >> 7);
  const int b = blockIdx.z;
  const int qy = q / OS, qx = q - qy * OS;
  float inv = gn[co] / sqrtf(vn[co] + 1e-5f);
  float sc = inv, sh = bn[co] - mn[co] * inv;
  float* vp = vm + (((size_t)b * NQ + q) * 4) * 128 + co;
  float v0, v1, v2, v3;
  if (t_base == 0) {
    v0 = v1 = v2 = v3 = 0.f;
  } else {
    v0 = vp[0]; v1 = vp[128]; v2 = vp[256]; v3 = vp[384];
  }
  const size_t rowstride = (size_t)S * 128;
  for (int t = 0; t < nt; ++t) {
    const float* p = pre + (((size_t)(t * 4 + b) * S + qy * 2) * S + qx * 2) * 128 + co;
    float x00 = p[0] * sc + sh;
    float x01 = p[128] * sc + sh;
    float x10 = p[rowstride] * sc + sh;
    float x11 = p[rowstride + 128] * sc + sh;
    float n0 = v0 + (x00 - v0) * 0.5f; float s0 = n0 >= 1.f ? 1.f : 0.f; v0 = n0 >= 1.f ? 0.f : n0;
    float n1 = v1 + (x01 - v1) * 0.5f; float s1 = n1 >= 1.f ? 1.f : 0.f; v1 = n1 >= 1.f ? 0.f : n1;
    float n2 = v2 + (x10 - v2) * 0.5f; float s2 = n2 >= 1.f ? 1.f : 0.f; v2 = n2 >= 1.f ? 0.f : n2;
    float n3 = v3 + (x11 - v3) * 0.5f; float s3 = n3 >= 1.f ? 1.f : 0.f; v3 = n3 >= 1.f ? 0.f : n3;
    float pooled = fmaxf(fmaxf(s0, s1), fmaxf(s2, s3));
    spk[((size_t)((t_base + t) * 4 + b) * NQ + q) * 128 + co] = __float2bfloat16(pooled);
  }
  if (t_base + nt < T_STEPS) {
    vp[0] = v0; vp[128] = v1; vp[256] = v2; vp[384] = v3;
  }
}

// ---- FC + final LIF ---------------------------------------------------------
__global__ __launch_bounds__(256) void fc_kernel(const __hip_bfloat16* __restrict__ a4,
                                                 const float* __restrict__ wfc,
                                                 const float* __restrict__ bfc,
                                                 float* __restrict__ z) {
  const int tb = blockIdx.x;
  const int tid = threadIdx.x;
  const __hip_bfloat16* a = a4 + (size_t)tb * 8192;
  float part[10];
#pragma unroll
  for (int o = 0; o < 10; ++o) part[o] = 0.f;
  for (int i = tid; i < 8192; i += 256) {
    int co = i >> 6, yx = i & 63;
    float av = __bfloat162float(a[yx * 128 + co]);
#pragma unroll
    for (int o = 0; o < 10; ++o) part[o] += av * wfc[o * 8192 + i];
  }
#pragma unroll
  for (int o = 0; o < 10; ++o)
    for (int off = 32; off > 0; off >>= 1) part[o] += __shfl_xor(part[o], off, 64);
  __shared__ float red[4][10];
  if ((tid & 63) == 0) {
#pragma unroll
    for (int o = 0; o < 10; ++o) red[tid >> 6][o] = part[o];
  }
  __syncthreads();
  if (tid < 10)
    z[tb * 10 + tid] = red[0][tid] + red[1][tid] + red[2][tid] + red[3][tid] + bfc[tid];
}

__global__ void out_lif_kernel(const float* __restrict__ z, float* __restrict__ out) {
  int i = threadIdx.x;
  if (i < 40) {
    float v = 0.f;
    for (int t = 0; t < T_STEPS; ++t) {
      float yv = z[t * 40 + i];
      float nv = v + (yv - v) * 0.5f;
      float s = (nv >= 1.0f) ? 1.0f : 0.0f;
      out[t * 40 + i] = s;
      v = (nv >= 1.0f) ? 0.f : nv;
    }
  }
}

extern "C" void kernel_launch(void* const* d_in, const int* in_sizes, int n_in,
                              void* d_out, int out_size, void* d_ws, size_t ws_size,
                              hipStream_t stream) {
  const float* x = (const float*)d_in[0];
  const float* w1 = (const float*)d_in[1];
  const float* g1 = (const float*)d_in[2];
  const float* b1 = (const float*)d_in[3];
  const float* m1 = (const float*)d_in[4];
  const float* v1 = (const float*)d_in[5];
  const float* w2 = (const float*)d_in[6];
  const float* g2 = (const float*)d_in[7];
  const float* b2 = (const float*)d_in[8];
  const float* m2 = (const float*)d_in[9];
  const float* v2 = (const float*)d_in[10];
  const float* w3 = (const float*)d_in[11];
  const float* g3 = (const float*)d_in[12];
  const float* b3 = (const float*)d_in[13];
  const float* m3 = (const float*)d_in[14];
  const float* v3 = (const float*)d_in[15];
  const float* w4 = (const float*)d_in[16];
  const float* g4 = (const float*)d_in[17];
  const float* b4 = (const float*)d_in[18];
  const float* m4 = (const float*)d_in[19];
  const float* v4 = (const float*)d_in[20];
  const float* wfc = (const float*)d_in[21];
  const float* bfc = (const float*)d_in[22];
  float* out = (float*)d_out;

  float* p = (float*)d_ws;
  __hip_bfloat16* wp2 = (__hip_bfloat16*)p; p += 221184;    // 442368 bf16
  __hip_bfloat16* wp3 = (__hip_bfloat16*)p; p += 221184;
  __hip_bfloat16* wp4 = (__hip_bfloat16*)p; p += 221184;
  __hip_bfloat16* spk1 = (__hip_bfloat16*)p; p += 16777216; // 33554432 bf16 (67MB)
  float* preH = p; p += 16777216;                           // 67MB, reused all layers
  float* xp = preH;                                         // alias: consumed by layer1
                                                            // before conv32 writes preH
  __hip_bfloat16* spk2 = (__hip_bfloat16*)p; p += 4194304;  // 8388608 bf16
  float* vm2 = p; p += 2097152;
  __hip_bfloat16* spk3 = (__hip_bfloat16*)p; p += 1048576;  // 2097152 bf16
  float* vm3 = p; p += 524288;
  __hip_bfloat16* spk4 = (__hip_bfloat16*)p; p += 262144;   // 524288 bf16
  float* vm4 = p; p += 131072;
  float* z = p; p += 640;

  prep_w3_kernel<<<dim3(576, 3), 256, 0, stream>>>(w2, w3, w4, wp2, wp3, wp4);
  pad_x_kernel<<<dim3(128, 130), 192, 0, stream>>>(x, xp);

  // layer 1 in two co-halves (independent slices; identical arithmetic)
  layer1_kernel<<<dim3(16, 16, 4), 256, 0, stream>>>(xp, w1, g1, b1, m1, v1, spk1, 0);
  layer1_kernel<<<dim3(16, 16, 4), 256, 0, stream>>>(xp, w1, g1, b1, m1, v1, spk1, 64);

  // layer 2 (S=64) in two t-halves; 8x8 tiles, 2 tb per block
  conv32p_kernel<64><<<dim3(64, 1, 16), 256, 0, stream>>>(spk1, wp2, preH, 0);
  lif_pool_kernel<64><<<dim3(512, 1, 4), 256, 0, stream>>>(preH, spk2, vm2, g2, b2, m2, v2, 0, 8);
  conv32p_kernel<64><<<dim3(64, 1, 16), 256, 0, stream>>>(spk1, wp2, preH, 32);
  lif_pool_kernel<64><<<dim3(512, 1, 4), 256, 0, stream>>>(preH, spk2, vm2, g2, b2, m2, v2, 8, 8);

  // layer 3 (S=32): 16 tiles x 32 pairs
  conv32p_kernel<32><<<dim3(16, 1, 32), 256, 0, stream>>>(spk2, wp3, preH, 0);
  lif_pool_kernel<32><<<dim3(128, 1, 4), 256, 0, stream>>>(preH, spk3, vm3, g3, b3, m3, v3, 0, 16);

  // layer 4 (S=16): 4 tiles x 64 tb, single-tb
  conv32_kernel<16><<<dim3(4, 1, 64), 256, 0, stream>>>(spk3, wp4, preH, 0);
  lif_pool_kernel<16><<<dim3(32, 1, 4), 256, 0, stream>>>(preH, spk4, vm4, g4, b4, m4, v4, 0, 16);

  fc_kernel<<<64, 256, 0, stream>>>(spk4, wfc, bfc, z);
  out_lif_kernel<<<1, 64, 0, stream>>>(z, out);
}

// Round 18
// 422.451 us; speedup vs baseline: 1.4137x; 1.4137x over previous
//
#include <hip/hip_runtime.h>
#include <hip/hip_bf16.h>
#include <math.h>

#define T_STEPS 16

typedef __attribute__((ext_vector_type(8))) short bf16x8;
typedef __attribute__((ext_vector_type(16))) float f32x16;
typedef __attribute__((ext_vector_type(2))) float f32x2;

// ---- prep (merged): w [co128][ci128][tap9] f32 -> wp [s3][tap9][kc16][co128][e8] bf16
__global__ __launch_bounds__(256) void prep_w3_kernel(
    const float* __restrict__ w2, const float* __restrict__ w3,
    const float* __restrict__ w4, __hip_bfloat16* __restrict__ wp2,
    __hip_bfloat16* __restrict__ wp3, __hip_bfloat16* __restrict__ wp4) {
  const float* w = blockIdx.y == 0 ? w2 : (blockIdx.y == 1 ? w3 : w4);
  __hip_bfloat16* wp = blockIdx.y == 0 ? wp2 : (blockIdx.y == 1 ? wp3 : wp4);
  int idx = blockIdx.x * 256 + threadIdx.x;
  if (idx >= 147456) return;
  int co = idx / 1152, rem = idx - co * 1152;
  int ci = rem / 9, tap = rem - ci * 9;
  float x = w[idx];
  float h = (float)__float2bfloat16(x);
  float r1 = x - h;
  float m = (float)__float2bfloat16(r1);
  float r2 = r1 - m;
  size_t base = (((size_t)tap * 16 + (ci >> 3)) * 128 + co) * 8 + (ci & 7);
  const size_t SSZ = 147456;
  wp[base] = __float2bfloat16(h);
  wp[SSZ + base] = __float2bfloat16(m);
  wp[2 * SSZ + base] = __float2bfloat16(r2);
}

// ---- pad_x: x [plane 128][128][128] -> xp [plane][130][132] zero-padded -----
__global__ __launch_bounds__(192) void pad_x_kernel(const float* __restrict__ x,
                                                    float* __restrict__ xp) {
  const int plane = blockIdx.x;
  const int row = blockIdx.y;
  const int c = threadIdx.x;
  if (c < 132) {
    float v = 0.f;
    int gr = row - 1, gc = c - 1;
    if ((unsigned)gr < 128u && (unsigned)gc < 128u)
      v = x[(size_t)plane * 16384 + gr * 128 + gc];
    xp[((size_t)plane * 130 + row) * 132 + c] = v;
  }
}

// ---- layer 1: conv(2->128)+BN+LIF+pool, pk-fma, t+1 load prefetch -----------
__global__ __launch_bounds__(256) void layer1_kernel(
    const float* __restrict__ xp, const float* __restrict__ w,
    const float* __restrict__ gn, const float* __restrict__ bn,
    const float* __restrict__ mn, const float* __restrict__ vn,
    __hip_bfloat16* __restrict__ out, int coBase) {
  const int tid = threadIdx.x;
  const int tile = blockIdx.x;
  const int ty0 = (tile >> 2) * 32, tx0 = (tile & 3) * 32;
  const int co0 = coBase + blockIdx.y * 4;
  const int b = blockIdx.z;
  const int qx2 = (tid & 15) * 2;
  const int qy2 = (tid >> 4) * 2;
  const int yq = ty0 + qy2;
  const int xq = tx0 + qx2;

  float wreg[2][9][4];
#pragma unroll
  for (int j = 0; j < 4; ++j)
#pragma unroll
    for (int ci = 0; ci < 2; ++ci)
#pragma unroll
      for (int tap = 0; tap < 9; ++tap)
        wreg[ci][tap][j] = w[(co0 + j) * 18 + ci * 9 + tap];

  float scale[4], shift[4];
#pragma unroll
  for (int j = 0; j < 4; ++j) {
    float inv = gn[co0 + j] / sqrtf(vn[co0 + j] + 1e-5f);
    scale[j] = inv;
    shift[j] = bn[co0 + j] - mn[co0 + j] * inv;
  }

  float vm[4][4];
#pragma unroll
  for (int j = 0; j < 4; ++j)
#pragma unroll
    for (int p = 0; p < 4; ++p) vm[j][p] = 0.f;

  // prefetch t = 0 input tile
  float iv[2][4][4];
  {
    const float* xpt = xp + (size_t)(b * 2) * 17160;
#pragma unroll
    for (int ci = 0; ci < 2; ++ci)
#pragma unroll
      for (int r = 0; r < 4; ++r)
        *(float4*)&iv[ci][r][0] =
            *(const float4*)(xpt + (size_t)(ci * 130 + yq + r) * 132 + xq);
  }

  for (int t = 0; t < T_STEPS; ++t) {
    float ivn[2][4][4];
    if (t + 1 < T_STEPS) {
      const float* xpn = xp + (size_t)(((t + 1) * 4 + b) * 2) * 17160;
#pragma unroll
      for (int ci = 0; ci < 2; ++ci)
#pragma unroll
        for (int r = 0; r < 4; ++r)
          *(float4*)&ivn[ci][r][0] =
              *(const float4*)(xpn + (size_t)(ci * 130 + yq + r) * 132 + xq);
    }

    f32x2 acc2[4][2];
#pragma unroll
    for (int j = 0; j < 4; ++j)
#pragma unroll
      for (int sy = 0; sy < 2; ++sy) acc2[j][sy] = (f32x2){0.f, 0.f};

#pragma unroll
    for (int ci = 0; ci < 2; ++ci)
#pragma unroll
      for (int tap = 0; tap < 9; ++tap) {
        const int dy = tap / 3, dx = tap - dy * 3;
#pragma unroll
        for (int sy = 0; sy < 2; ++sy) {
          f32x2 x2;
          x2[0] = iv[ci][sy + dy][dx];
          x2[1] = iv[ci][sy + dy][dx + 1];
#pragma unroll
          for (int j = 0; j < 4; ++j) {
            f32x2 w2 = {wreg[ci][tap][j], wreg[ci][tap][j]};
            acc2[j][sy] += w2 * x2;     // -> v_pk_fma_f32
          }
        }
      }

    const int py = (ty0 >> 1) + (tid >> 4);
    const int px = (tx0 >> 1) + (tid & 15);
    short4 pk;
    short* pks = (short*)&pk;
#pragma unroll
    for (int j = 0; j < 4; ++j) {
      float mx = -1e30f;
#pragma unroll
      for (int p = 0; p < 4; ++p) {
        float yv = acc2[j][p >> 1][p & 1] * scale[j] + shift[j];
        float nv = vm[j][p] + (yv - vm[j][p]) * 0.5f;
        mx = fmaxf(mx, nv);
        vm[j][p] = (nv >= 1.0f) ? 0.f : nv;
      }
      __hip_bfloat16 bv = __float2bfloat16(mx >= 1.0f ? 1.0f : 0.0f);
      pks[j] = *(short*)&bv;
    }
    *(short4*)(out + (((size_t)(t * 4 + b) * 64 + py) * 64 + px) * 128 + co0) = pk;

    if (t + 1 < T_STEPS) {
#pragma unroll
      for (int ci = 0; ci < 2; ++ci)
#pragma unroll
        for (int r = 0; r < 4; ++r)
#pragma unroll
          for (int c = 0; c < 4; ++c) iv[ci][r][c] = ivn[ci][r][c];
    }
  }
}

// ---- conv layers 2-3: 8x8 tile, TWO consecutive tb per block (R15-exact) ----
template <int S>
__global__ __launch_bounds__(256) void conv32p_kernel(
    const __hip_bfloat16* __restrict__ spk, const __hip_bfloat16* __restrict__ wp,
    float* __restrict__ pre, int tb_base) {
  constexpr int TILES_X = S / 8;
  const int tile = blockIdx.x;
  const int ty0 = (tile / TILES_X) * 8;
  const int tx0 = (tile % TILES_X) * 8;
  const int pair = blockIdx.z;
  const int tbl0 = pair * 2;
  const int tb0 = tb_base + tbl0;
  const int tid = threadIdx.x;
  const int lane = tid & 63;
  const int wv = tid >> 6;

  __shared__ uint4 At4[2][1600];

#pragma unroll
  for (int i = 0; i < 2; ++i) {
    const __hip_bfloat16* sp = spk + (size_t)(tb0 + i) * S * S * 128;
    for (int job = tid; job < 1600; job += 256) {
      int c8 = job & 15, si = job >> 4;
      int y = (si * 6554) >> 16;
      int xx = si - y * 10;
      int gy = ty0 - 1 + y, gx = tx0 - 1 + xx;
      uint4 v = make_uint4(0u, 0u, 0u, 0u);
      if ((unsigned)gy < (unsigned)S && (unsigned)gx < (unsigned)S)
        v = *(const uint4*)(sp + ((size_t)(gy * S + gx)) * 128 + c8 * 8);
      At4[i][(y * 10 + xx) * 16 + (c8 ^ (xx & 7))] = v;
    }
  }
  __syncthreads();

  const int l31 = lane & 31, hh = lane >> 5;
  const int co = wv * 32 + l31;
  const int ly = l31 >> 3, lx = lane & 7;

  f32x16 acc0[2], acc1[2];
#pragma unroll
  for (int m = 0; m < 2; ++m)
#pragma unroll
    for (int r = 0; r < 16; ++r) { acc0[m][r] = 0.f; acc1[m][r] = 0.f; }

  const short* wpb = (const short*)wp + (size_t)co * 8;

  for (int tap = 0; tap < 9; ++tap) {
    const int dy = tap / 3, dx = tap - dy * 3;
    const int xx = lx + dx;
    const int sx7 = xx & 7;
#pragma unroll
    for (int kk = 0; kk < 8; ++kk) {
      const int kc = kk * 2 + hh;
      bf16x8 a0[2], a1[2];
#pragma unroll
      for (int m = 0; m < 2; ++m) {
        const int slot = ((m * 4 + ly + dy) * 10 + xx) * 16 + (kc ^ sx7);
        a0[m] = *(const bf16x8*)(At4[0] + slot);
        a1[m] = *(const bf16x8*)(At4[1] + slot);
      }
#pragma unroll
      for (int s = 0; s < 3; ++s) {
        bf16x8 bfr = *(const bf16x8*)(wpb + ((size_t)(s * 9 + tap) * 16 + kc) * 1024);
#pragma unroll
        for (int m = 0; m < 2; ++m)
          acc0[m] = __builtin_amdgcn_mfma_f32_32x32x16_bf16(a0[m], bfr, acc0[m], 0, 0, 0);
#pragma unroll
        for (int m = 0; m < 2; ++m)
          acc1[m] = __builtin_amdgcn_mfma_f32_32x32x16_bf16(a1[m], bfr, acc1[m], 0, 0, 0);
      }
    }
  }

  float* po0 = pre + (size_t)tbl0 * S * S * 128 + co;
  float* po1 = pre + (size_t)(tbl0 + 1) * S * S * 128 + co;
#pragma unroll
  for (int m = 0; m < 2; ++m)
#pragma unroll
    for (int r = 0; r < 16; ++r) {
      int row = (r & 3) + 8 * (r >> 2) + 4 * hh;
      int p = m * 32 + row;
      size_t off = ((size_t)(ty0 + (p >> 3)) * S + tx0 + (p & 7)) * 128;
      po0[off] = acc0[m][r];
      po1[off] = acc1[m][r];
    }
}

// ---- conv layer 4: 8x8 tile, single tb (R15-exact) --------------------------
template <int S>
__global__ __launch_bounds__(256) void conv32_kernel(
    const __hip_bfloat16* __restrict__ spk, const __hip_bfloat16* __restrict__ wp,
    float* __restrict__ pre, int t_base) {
  constexpr int TILES_X = S / 8;
  const int tile = blockIdx.x;
  const int ty0 = (tile / TILES_X) * 8;
  const int tx0 = (tile % TILES_X) * 8;
  const int tbl = blockIdx.z;
  const int tbg = t_base * 4 + tbl;
  const int tid = threadIdx.x;
  const int lane = tid & 63;
  const int wv = tid >> 6;

  __shared__ uint4 At4[1600];

  const __hip_bfloat16* sp = spk + (size_t)tbg * S * S * 128;
#pragma unroll
  for (int k = 0; k < 7; ++k) {
    int job = k * 256 + tid;
    if (job < 1600) {
      int c8 = job & 15, si = job >> 4;
      int y = (si * 6554) >> 16;
      int xx = si - y * 10;
      int gy = ty0 - 1 + y, gx = tx0 - 1 + xx;
      uint4 v = make_uint4(0u, 0u, 0u, 0u);
      if ((unsigned)gy < (unsigned)S && (unsigned)gx < (unsigned)S)
        v = *(const uint4*)(sp + ((size_t)(gy * S + gx)) * 128 + c8 * 8);
      At4[(y * 10 + xx) * 16 + (c8 ^ (xx & 7))] = v;
    }
  }
  __syncthreads();

  const int l31 = lane & 31, hh = lane >> 5;
  const int co = wv * 32 + l31;
  const int ly = l31 >> 3, lx = lane & 7;

  f32x16 acc[2];
#pragma unroll
  for (int m = 0; m < 2; ++m)
#pragma unroll
    for (int r = 0; r < 16; ++r) acc[m][r] = 0.f;

  const short* wpb = (const short*)wp + (size_t)co * 8;

  for (int tap = 0; tap < 9; ++tap) {
    const int dy = tap / 3, dx = tap - dy * 3;
    const int xx = lx + dx;
    const int sx7 = xx & 7;
#pragma unroll
    for (int kk = 0; kk < 8; ++kk) {
      const int kc = kk * 2 + hh;
      bf16x8 a[2];
#pragma unroll
      for (int m = 0; m < 2; ++m)
        a[m] = *(const bf16x8*)(At4 + ((m * 4 + ly + dy) * 10 + xx) * 16 + (kc ^ sx7));
#pragma unroll
      for (int s = 0; s < 3; ++s) {
        bf16x8 bfr = *(const bf16x8*)(wpb + ((size_t)(s * 9 + tap) * 16 + kc) * 1024);
#pragma unroll
        for (int m = 0; m < 2; ++m)
          acc[m] = __builtin_amdgcn_mfma_f32_32x32x16_bf16(a[m], bfr, acc[m], 0, 0, 0);
      }
    }
  }

  float* po = pre + (size_t)tbl * S * S * 128 + co;
#pragma unroll
  for (int m = 0; m < 2; ++m)
#pragma unroll
    for (int r = 0; r < 16; ++r) {
      int row = (r & 3) + 8 * (r >> 2) + 4 * hh;
      int p = m * 32 + row;
      po[((size_t)(ty0 + (p >> 3)) * S + tx0 + (p & 7)) * 128] = acc[m][r];
    }
}

// ---- BN + LIF + pool pass (layers 2-4) --------------------------------------
template <int S>
__global__ __launch_bounds__(256) void lif_pool_kernel(
    const float* __restrict__ pre, __hip_bfloat16* __restrict__ spk,
    float* __restrict__ vm, const float* __restrict__ gn,
    const float* __restrict__ bn, const float* __restrict__ mn,
    const float* __restrict__ vn, int t_base, int nt) {
  constexpr int OS = S / 2, NQ = OS * OS;
  const int tid = threadIdx.x;
  const int co = tid & 127;
  const int q = blockIdx.x * 2 + (tid >> 7);
  const int b = blockIdx.z;
  const int qy = q / OS, qx = q - qy * OS;
  float inv = gn[co] / sqrtf(vn[co] + 1e-5f);
  float sc = inv, sh = bn[co] - mn[co] * inv;
  float* vp = vm + (((size_t)b * NQ + q) * 4) * 128 + co;
  float v0, v1, v2, v3;
  if (t_base == 0) {
    v0 = v1 = v2 = v3 = 0.f;
  } else {
    v0 = vp[0]; v1 = vp[128]; v2 = vp[256]; v3 = vp[384];
  }
  const size_t rowstride = (size_t)S * 128;
  for (int t = 0; t < nt; ++t) {
    const float* p = pre + (((size_t)(t * 4 + b) * S + qy * 2) * S + qx * 2) * 128 + co;
    float x00 = p[0] * sc + sh;
    float x01 = p[128] * sc + sh;
    float x10 = p[rowstride] * sc + sh;
    float x11 = p[rowstride + 128] * sc + sh;
    float n0 = v0 + (x00 - v0) * 0.5f; float s0 = n0 >= 1.f ? 1.f : 0.f; v0 = n0 >= 1.f ? 0.f : n0;
    float n1 = v1 + (x01 - v1) * 0.5f; float s1 = n1 >= 1.f ? 1.f : 0.f; v1 = n1 >= 1.f ? 0.f : n1;
    float n2 = v2 + (x10 - v2) * 0.5f; float s2 = n2 >= 1.f ? 1.f : 0.f; v2 = n2 >= 1.f ? 0.f : n2;
    float n3 = v3 + (x11 - v3) * 0.5f; float s3 = n3 >= 1.f ? 1.f : 0.f; v3 = n3 >= 1.f ? 0.f : n3;
    float pooled = fmaxf(fmaxf(s0, s1), fmaxf(s2, s3));
    spk[((size_t)((t_base + t) * 4 + b) * NQ + q) * 128 + co] = __float2bfloat16(pooled);
  }
  if (t_base + nt < T_STEPS) {
    vp[0] = v0; vp[128] = v1; vp[256] = v2; vp[384] = v3;
  }
}

// ---- FC + final LIF ---------------------------------------------------------
__global__ __launch_bounds__(256) void fc_kernel(const __hip_bfloat16* __restrict__ a4,
                                                 const float* __restrict__ wfc,
                                                 const float* __restrict__ bfc,
                                                 float* __restrict__ z) {
  const int tb = blockIdx.x;
  const int tid = threadIdx.x;
  const __hip_bfloat16* a = a4 + (size_t)tb * 8192;
  float part[10];
#pragma unroll
  for (int o = 0; o < 10; ++o) part[o] = 0.f;
  for (int i = tid; i < 8192; i += 256) {
    int co = i >> 6, yx = i & 63;
    float av = __bfloat162float(a[yx * 128 + co]);
#pragma unroll
    for (int o = 0; o < 10; ++o) part[o] += av * wfc[o * 8192 + i];
  }
#pragma unroll
  for (int o = 0; o < 10; ++o)
    for (int off = 32; off > 0; off >>= 1) part[o] += __shfl_xor(part[o], off, 64);
  __shared__ float red[4][10];
  if ((tid & 63) == 0) {
#pragma unroll
    for (int o = 0; o < 10; ++o) red[tid >> 6][o] = part[o];
  }
  __syncthreads();
  if (tid < 10)
    z[tb * 10 + tid] = red[0][tid] + red[1][tid] + red[2][tid] + red[3][tid] + bfc[tid];
}

__global__ void out_lif_kernel(const float* __restrict__ z, float* __restrict__ out) {
  int i = threadIdx.x;
  if (i < 40) {
    float v = 0.f;
    for (int t = 0; t < T_STEPS; ++t) {
      float yv = z[t * 40 + i];
      float nv = v + (yv - v) * 0.5f;
      float s = (nv >= 1.0f) ? 1.0f : 0.0f;
      out[t * 40 + i] = s;
      v = (nv >= 1.0f) ? 0.f : nv;
    }
  }
}

extern "C" void kernel_launch(void* const* d_in, const int* in_sizes, int n_in,
                              void* d_out, int out_size, void* d_ws, size_t ws_size,
                              hipStream_t stream) {
  const float* x = (const float*)d_in[0];
  const float* w1 = (const float*)d_in[1];
  const float* g1 = (const float*)d_in[2];
  const float* b1 = (const float*)d_in[3];
  const float* m1 = (const float*)d_in[4];
  const float* v1 = (const float*)d_in[5];
  const float* w2 = (const float*)d_in[6];
  const float* g2 = (const float*)d_in[7];
  const float* b2 = (const float*)d_in[8];
  const float* m2 = (const float*)d_in[9];
  const float* v2 = (const float*)d_in[10];
  const float* w3 = (const float*)d_in[11];
  const float* g3 = (const float*)d_in[12];
  const float* b3 = (const float*)d_in[13];
  const float* m3 = (const float*)d_in[14];
  const float* v3 = (const float*)d_in[15];
  const float* w4 = (const float*)d_in[16];
  const float* g4 = (const float*)d_in[17];
  const float* b4 = (const float*)d_in[18];
  const float* m4 = (const float*)d_in[19];
  const float* v4 = (const float*)d_in[20];
  const float* wfc = (const float*)d_in[21];
  const float* bfc = (const float*)d_in[22];
  float* out = (float*)d_out;

  float* p = (float*)d_ws;
  __hip_bfloat16* wp2 = (__hip_bfloat16*)p; p += 221184;    // 442368 bf16
  __hip_bfloat16* wp3 = (__hip_bfloat16*)p; p += 221184;
  __hip_bfloat16* wp4 = (__hip_bfloat16*)p; p += 221184;
  __hip_bfloat16* spk1 = (__hip_bfloat16*)p; p += 16777216; // 33554432 bf16 (67MB)
  float* preH = p; p += 16777216;                           // 67MB, reused all layers
  float* xp = preH;                                         // alias: consumed by layer1
                                                            // before conv32 writes preH
  __hip_bfloat16* spk2 = (__hip_bfloat16*)p; p += 4194304;  // 8388608 bf16
  float* vm2 = p; p += 2097152;
  __hip_bfloat16* spk3 = (__hip_bfloat16*)p; p += 1048576;  // 2097152 bf16
  float* vm3 = p; p += 524288;
  __hip_bfloat16* spk4 = (__hip_bfloat16*)p; p += 262144;   // 524288 bf16
  float* vm4 = p; p += 131072;
  float* z = p; p += 640;

  prep_w3_kernel<<<dim3(576, 3), 256, 0, stream>>>(w2, w3, w4, wp2, wp3, wp4);
  pad_x_kernel<<<dim3(128, 130), 192, 0, stream>>>(x, xp);

  // layer 1 in two co-halves (independent slices; identical arithmetic)
  layer1_kernel<<<dim3(16, 16, 4), 256, 0, stream>>>(xp, w1, g1, b1, m1, v1, spk1, 0);
  layer1_kernel<<<dim3(16, 16, 4), 256, 0, stream>>>(xp, w1, g1, b1, m1, v1, spk1, 64);

  // layer 2 (S=64) in two t-halves; 8x8 tiles, 2 tb per block
  conv32p_kernel<64><<<dim3(64, 1, 16), 256, 0, stream>>>(spk1, wp2, preH, 0);
  lif_pool_kernel<64><<<dim3(512, 1, 4), 256, 0, stream>>>(preH, spk2, vm2, g2, b2, m2, v2, 0, 8);
  conv32p_kernel<64><<<dim3(64, 1, 16), 256, 0, stream>>>(spk1, wp2, preH, 32);
  lif_pool_kernel<64><<<dim3(512, 1, 4), 256, 0, stream>>>(preH, spk2, vm2, g2, b2, m2, v2, 8, 8);

  // layer 3 (S=32): 16 tiles x 32 pairs
  conv32p_kernel<32><<<dim3(16, 1, 32), 256, 0, stream>>>(spk2, wp3, preH, 0);
  lif_pool_kernel<32><<<dim3(128, 1, 4), 256, 0, stream>>>(preH, spk3, vm3, g3, b3, m3, v3, 0, 16);

  // layer 4 (S=16): 4 tiles x 64 tb, single-tb
  conv32_kernel<16><<<dim3(4, 1, 64), 256, 0, stream>>>(spk3, wp4, preH, 0);
  lif_pool_kernel<16><<<dim3(32, 1, 4), 256, 0, stream>>>(preH, spk4, vm4, g4, b4, m4, v4, 0, 16);

  fc_kernel<<<64, 256, 0, stream>>>(spk4, wfc, bfc, z);
  out_lif_kernel<<<1, 64, 0, stream>>>(z, out);
}

// Round 19
// 417.236 us; speedup vs baseline: 1.4314x; 1.0125x over previous
//
#include <hip/hip_runtime.h>
#include <hip/hip_bf16.h>
#include <math.h>

#define T_STEPS 16

typedef __attribute__((ext_vector_type(8))) short bf16x8;
typedef __attribute__((ext_vector_type(16))) float f32x16;
typedef __attribute__((ext_vector_type(2))) float f32x2;

// ---- prep (merged): w [co128][ci128][tap9] f32 -> wp [s3][tap9][kc16][co128][e8] bf16
__global__ __launch_bounds__(256) void prep_w3_kernel(
    const float* __restrict__ w2, const float* __restrict__ w3,
    const float* __restrict__ w4, __hip_bfloat16* __restrict__ wp2,
    __hip_bfloat16* __restrict__ wp3, __hip_bfloat16* __restrict__ wp4) {
  const float* w = blockIdx.y == 0 ? w2 : (blockIdx.y == 1 ? w3 : w4);
  __hip_bfloat16* wp = blockIdx.y == 0 ? wp2 : (blockIdx.y == 1 ? wp3 : wp4);
  int idx = blockIdx.x * 256 + threadIdx.x;
  if (idx >= 147456) return;
  int co = idx / 1152, rem = idx - co * 1152;
  int ci = rem / 9, tap = rem - ci * 9;
  float x = w[idx];
  float h = (float)__float2bfloat16(x);
  float r1 = x - h;
  float m = (float)__float2bfloat16(r1);
  float r2 = r1 - m;
  size_t base = (((size_t)tap * 16 + (ci >> 3)) * 128 + co) * 8 + (ci & 7);
  const size_t SSZ = 147456;
  wp[base] = __float2bfloat16(h);
  wp[SSZ + base] = __float2bfloat16(m);
  wp[2 * SSZ + base] = __float2bfloat16(r2);
}

// ---- pad_x: x [plane 128][128][128] -> xp [plane][130][132] zero-padded -----
__global__ __launch_bounds__(192) void pad_x_kernel(const float* __restrict__ x,
                                                    float* __restrict__ xp) {
  const int plane = blockIdx.x;
  const int row = blockIdx.y;
  const int c = threadIdx.x;
  if (c < 132) {
    float v = 0.f;
    int gr = row - 1, gc = c - 1;
    if ((unsigned)gr < 128u && (unsigned)gc < 128u)
      v = x[(size_t)plane * 16384 + gr * 128 + gc];
    xp[((size_t)plane * 130 + row) * 132 + c] = v;
  }
}

// ---- layer 1: conv(2->128)+BN+LIF+pool, SGPR weights, packed f32x2 FMA ------
__global__ __launch_bounds__(256) void layer1_kernel(
    const float* __restrict__ xp, const float* __restrict__ w,
    const float* __restrict__ gn, const float* __restrict__ bn,
    const float* __restrict__ mn, const float* __restrict__ vn,
    __hip_bfloat16* __restrict__ out, int coBase) {
  const int tid = threadIdx.x;
  const int tile = blockIdx.x;
  const int ty0 = (tile >> 2) * 32, tx0 = (tile & 3) * 32;
  const int co0 = coBase + blockIdx.y * 4;
  const int b = blockIdx.z;
  const int qx2 = (tid & 15) * 2;
  const int qy2 = (tid >> 4) * 2;
  const int yq = ty0 + qy2;
  const int xq = tx0 + qx2;

  float wreg[2][9][4];
#pragma unroll
  for (int j = 0; j < 4; ++j)
#pragma unroll
    for (int ci = 0; ci < 2; ++ci)
#pragma unroll
      for (int tap = 0; tap < 9; ++tap)
        wreg[ci][tap][j] = w[(co0 + j) * 18 + ci * 9 + tap];

  float scale[4], shift[4];
#pragma unroll
  for (int j = 0; j < 4; ++j) {
    float inv = gn[co0 + j] / sqrtf(vn[co0 + j] + 1e-5f);
    scale[j] = inv;
    shift[j] = bn[co0 + j] - mn[co0 + j] * inv;
  }

  float vm[4][4];
#pragma unroll
  for (int j = 0; j < 4; ++j)
#pragma unroll
    for (int p = 0; p < 4; ++p) vm[j][p] = 0.f;

  for (int t = 0; t < T_STEPS; ++t) {
    const float* xpt = xp + (size_t)((t * 4 + b) * 2) * 17160;
    float iv[2][4][4];
#pragma unroll
    for (int ci = 0; ci < 2; ++ci)
#pragma unroll
      for (int r = 0; r < 4; ++r)
        *(float4*)&iv[ci][r][0] =
            *(const float4*)(xpt + (size_t)(ci * 130 + yq + r) * 132 + xq);

    f32x2 acc2[4][2];
#pragma unroll
    for (int j = 0; j < 4; ++j)
#pragma unroll
      for (int sy = 0; sy < 2; ++sy) acc2[j][sy] = (f32x2){0.f, 0.f};

#pragma unroll
    for (int ci = 0; ci < 2; ++ci)
#pragma unroll
      for (int tap = 0; tap < 9; ++tap) {
        const int dy = tap / 3, dx = tap - dy * 3;
#pragma unroll
        for (int sy = 0; sy < 2; ++sy) {
          f32x2 x2;
          x2[0] = iv[ci][sy + dy][dx];
          x2[1] = iv[ci][sy + dy][dx + 1];
#pragma unroll
          for (int j = 0; j < 4; ++j) {
            f32x2 w2 = {wreg[ci][tap][j], wreg[ci][tap][j]};
            acc2[j][sy] += w2 * x2;     // -> v_pk_fma_f32
          }
        }
      }

    const int py = (ty0 >> 1) + (tid >> 4);
    const int px = (tx0 >> 1) + (tid & 15);
    short4 pk;
    short* pks = (short*)&pk;
#pragma unroll
    for (int j = 0; j < 4; ++j) {
      float mx = -1e30f;
#pragma unroll
      for (int p = 0; p < 4; ++p) {
        float yv = acc2[j][p >> 1][p & 1] * scale[j] + shift[j];
        float nv = vm[j][p] + (yv - vm[j][p]) * 0.5f;
        mx = fmaxf(mx, nv);
        vm[j][p] = (nv >= 1.0f) ? 0.f : nv;
      }
      __hip_bfloat16 bv = __float2bfloat16(mx >= 1.0f ? 1.0f : 0.0f);
      pks[j] = *(short*)&bv;
    }
    *(short4*)(out + (((size_t)(t * 4 + b) * 64 + py) * 64 + px) * 128 + co0) = pk;
  }
}

// ---- conv layers 2-3: 8x8 tile, TWO consecutive tb per block ----------------
template <int S>
__global__ __launch_bounds__(256) void conv32p_kernel(
    const __hip_bfloat16* __restrict__ spk, const __hip_bfloat16* __restrict__ wp,
    float* __restrict__ pre, int tb_base) {
  constexpr int TILES_X = S / 8;
  const int tile = blockIdx.x;
  const int ty0 = (tile / TILES_X) * 8;
  const int tx0 = (tile % TILES_X) * 8;
  const int pair = blockIdx.z;
  const int tbl0 = pair * 2;
  const int tb0 = tb_base + tbl0;
  const int tid = threadIdx.x;
  const int lane = tid & 63;
  const int wv = tid >> 6;

  __shared__ uint4 At4[2][1600];

#pragma unroll
  for (int i = 0; i < 2; ++i) {
    const __hip_bfloat16* sp = spk + (size_t)(tb0 + i) * S * S * 128;
    for (int job = tid; job < 1600; job += 256) {
      int c8 = job & 15, si = job >> 4;
      int y = (si * 6554) >> 16;
      int xx = si - y * 10;
      int gy = ty0 - 1 + y, gx = tx0 - 1 + xx;
      uint4 v = make_uint4(0u, 0u, 0u, 0u);
      if ((unsigned)gy < (unsigned)S && (unsigned)gx < (unsigned)S)
        v = *(const uint4*)(sp + ((size_t)(gy * S + gx)) * 128 + c8 * 8);
      At4[i][(y * 10 + xx) * 16 + (c8 ^ (xx & 7))] = v;
    }
  }
  __syncthreads();

  const int l31 = lane & 31, hh = lane >> 5;
  const int co = wv * 32 + l31;
  const int ly = l31 >> 3, lx = lane & 7;

  f32x16 acc0[2], acc1[2];
#pragma unroll
  for (int m = 0; m < 2; ++m)
#pragma unroll
    for (int r = 0; r < 16; ++r) { acc0[m][r] = 0.f; acc1[m][r] = 0.f; }

  const short* wpb = (const short*)wp + (size_t)co * 8;

  for (int tap = 0; tap < 9; ++tap) {
    const int dy = tap / 3, dx = tap - dy * 3;
    const int xx = lx + dx;
    const int sx7 = xx & 7;
#pragma unroll
    for (int kk = 0; kk < 8; ++kk) {
      const int kc = kk * 2 + hh;
      bf16x8 a0[2], a1[2];
#pragma unroll
      for (int m = 0; m < 2; ++m) {
        const int slot = ((m * 4 + ly + dy) * 10 + xx) * 16 + (kc ^ sx7);
        a0[m] = *(const bf16x8*)(At4[0] + slot);
        a1[m] = *(const bf16x8*)(At4[1] + slot);
      }
#pragma unroll
      for (int s = 0; s < 3; ++s) {
        bf16x8 bfr = *(const bf16x8*)(wpb + ((size_t)(s * 9 + tap) * 16 + kc) * 1024);
#pragma unroll
        for (int m = 0; m < 2; ++m)
          acc0[m] = __builtin_amdgcn_mfma_f32_32x32x16_bf16(a0[m], bfr, acc0[m], 0, 0, 0);
#pragma unroll
        for (int m = 0; m < 2; ++m)
          acc1[m] = __builtin_amdgcn_mfma_f32_32x32x16_bf16(a1[m], bfr, acc1[m], 0, 0, 0);
      }
    }
  }

  float* po0 = pre + (size_t)tbl0 * S * S * 128 + co;
  float* po1 = pre + (size_t)(tbl0 + 1) * S * S * 128 + co;
#pragma unroll
  for (int m = 0; m < 2; ++m)
#pragma unroll
    for (int r = 0; r < 16; ++r) {
      int row = (r & 3) + 8 * (r >> 2) + 4 * hh;
      int p = m * 32 + row;
      size_t off = ((size_t)(ty0 + (p >> 3)) * S + tx0 + (p & 7)) * 128;
      po0[off] = acc0[m][r];
      po1[off] = acc1[m][r];
    }
}

// ---- conv layer 4: 8x8 tile, single tb (parallelism-bound) ------------------
template <int S>
__global__ __launch_bounds__(256) void conv32_kernel(
    const __hip_bfloat16* __restrict__ spk, const __hip_bfloat16* __restrict__ wp,
    float* __restrict__ pre, int t_base) {
  constexpr int TILES_X = S / 8;
  const int tile = blockIdx.x;
  const int ty0 = (tile / TILES_X) * 8;
  const int tx0 = (tile % TILES_X) * 8;
  const int tbl = blockIdx.z;
  const int tbg = t_base * 4 + tbl;
  const int tid = threadIdx.x;
  const int lane = tid & 63;
  const int wv = tid >> 6;

  __shared__ uint4 At4[1600];

  const __hip_bfloat16* sp = spk + (size_t)tbg * S * S * 128;
#pragma unroll
  for (int k = 0; k < 7; ++k) {
    int job = k * 256 + tid;
    if (job < 1600) {
      int c8 = job & 15, si = job >> 4;
      int y = (si * 6554) >> 16;
      int xx = si - y * 10;
      int gy = ty0 - 1 + y, gx = tx0 - 1 + xx;
      uint4 v = make_uint4(0u, 0u, 0u, 0u);
      if ((unsigned)gy < (unsigned)S && (unsigned)gx < (unsigned)S)
        v = *(const uint4*)(sp + ((size_t)(gy * S + gx)) * 128 + c8 * 8);
      At4[(y * 10 + xx) * 16 + (c8 ^ (xx & 7))] = v;
    }
  }
  __syncthreads();

  const int l31 = lane & 31, hh = lane >> 5;
  const int co = wv * 32 + l31;
  const int ly = l31 >> 3, lx = lane & 7;

  f32x16 acc[2];
#pragma unroll
  for (int m = 0; m < 2; ++m)
#pragma unroll
    for (int r = 0; r < 16; ++r) acc[m][r] = 0.f;

  const short* wpb = (const short*)wp + (size_t)co * 8;

  for (int tap = 0; tap < 9; ++tap) {
    const int dy = tap / 3, dx = tap - dy * 3;
    const int xx = lx + dx;
    const int sx7 = xx & 7;
#pragma unroll
    for (int kk = 0; kk < 8; ++kk) {
      const int kc = kk * 2 + hh;
      bf16x8 a[2];
#pragma unroll
      for (int m = 0; m < 2; ++m)
        a[m] = *(const bf16x8*)(At4 + ((m * 4 + ly + dy) * 10 + xx) * 16 + (kc ^ sx7));
#pragma unroll
      for (int s = 0; s < 3; ++s) {
        bf16x8 bfr = *(const bf16x8*)(wpb + ((size_t)(s * 9 + tap) * 16 + kc) * 1024);
#pragma unroll
        for (int m = 0; m < 2; ++m)
          acc[m] = __builtin_amdgcn_mfma_f32_32x32x16_bf16(a[m], bfr, acc[m], 0, 0, 0);
      }
    }
  }

  float* po = pre + (size_t)tbl * S * S * 128 + co;
#pragma unroll
  for (int m = 0; m < 2; ++m)
#pragma unroll
    for (int r = 0; r < 16; ++r) {
      int row = (r & 3) + 8 * (r >> 2) + 4 * hh;
      int p = m * 32 + row;
      po[((size_t)(ty0 + (p >> 3)) * S + tx0 + (p & 7)) * 128] = acc[m][r];
    }
}

// ---- BN + LIF + pool pass (layers 2-4) --------------------------------------
template <int S>
__global__ __launch_bounds__(256) void lif_pool_kernel(
    const float* __restrict__ pre, __hip_bfloat16* __restrict__ spk,
    float* __restrict__ vm, const float* __restrict__ gn,
    const float* __restrict__ bn, const float* __restrict__ mn,
    const float* __restrict__ vn, int t_base, int nt) {
  constexpr int OS = S / 2, NQ = OS * OS;
  const int tid = threadIdx.x;
  const int co = tid & 127;
  const int q = blockIdx.x * 2 + (tid >> 7);
  const int b = blockIdx.z;
  const int qy = q / OS, qx = q - qy * OS;
  float inv = gn[co] / sqrtf(vn[co] + 1e-5f);
  float sc = inv, sh = bn[co] - mn[co] * inv;
  float* vp = vm + (((size_t)b * NQ + q) * 4) * 128 + co;
  float v0, v1, v2, v3;
  if (t_base == 0) {
    v0 = v1 = v2 = v3 = 0.f;
  } else {
    v0 = vp[0]; v1 = vp[128]; v2 = vp[256]; v3 = vp[384];
  }
  const size_t rowstride = (size_t)S * 128;
  for (int t = 0; t < nt; ++t) {
    const float* p = pre + (((size_t)(t * 4 + b) * S + qy * 2) * S + qx * 2) * 128 + co;
    float x00 = p[0] * sc + sh;
    float x01 = p[128] * sc + sh;
    float x10 = p[rowstride] * sc + sh;
    float x11 = p[rowstride + 128] * sc + sh;
    float n0 = v0 + (x00 - v0) * 0.5f; float s0 = n0 >= 1.f ? 1.f : 0.f; v0 = n0 >= 1.f ? 0.f : n0;
    float n1 = v1 + (x01 - v1) * 0.5f; float s1 = n1 >= 1.f ? 1.f : 0.f; v1 = n1 >= 1.f ? 0.f : n1;
    float n2 = v2 + (x10 - v2) * 0.5f; float s2 = n2 >= 1.f ? 1.f : 0.f; v2 = n2 >= 1.f ? 0.f : n2;
    float n3 = v3 + (x11 - v3) * 0.5f; float s3 = n3 >= 1.f ? 1.f : 0.f; v3 = n3 >= 1.f ? 0.f : n3;
    float pooled = fmaxf(fmaxf(s0, s1), fmaxf(s2, s3));
    spk[((size_t)((t_base + t) * 4 + b) * NQ + q) * 128 + co] = __float2bfloat16(pooled);
  }
  if (t_base + nt < T_STEPS) {
    vp[0] = v0; vp[128] = v1; vp[256] = v2; vp[384] = v3;
  }
}

// ---- FC + final LIF ---------------------------------------------------------
__global__ __launch_bounds__(256) void fc_kernel(const __hip_bfloat16* __restrict__ a4,
                                                 const float* __restrict__ wfc,
                                                 const float* __restrict__ bfc,
                                                 float* __restrict__ z) {
  const int tb = blockIdx.x;
  const int tid = threadIdx.x;
  const __hip_bfloat16* a = a4 + (size_t)tb * 8192;
  float part[10];
#pragma unroll
  for (int o = 0; o < 10; ++o) part[o] = 0.f;
  for (int i = tid; i < 8192; i += 256) {
    int co = i >> 6, yx = i & 63;
    float av = __bfloat162float(a[yx * 128 + co]);
#pragma unroll
    for (int o = 0; o < 10; ++o) part[o] += av * wfc[o * 8192 + i];
  }
#pragma unroll
  for (int o = 0; o < 10; ++o)
    for (int off = 32; off > 0; off >>= 1) part[o] += __shfl_xor(part[o], off, 64);
  __shared__ float red[4][10];
  if ((tid & 63) == 0) {
#pragma unroll
    for (int o = 0; o < 10; ++o) red[tid >> 6][o] = part[o];
  }
  __syncthreads();
  if (tid < 10)
    z[tb * 10 + tid] = red[0][tid] + red[1][tid] + red[2][tid] + red[3][tid] + bfc[tid];
}

__global__ void out_lif_kernel(const float* __restrict__ z, float* __restrict__ out) {
  int i = threadIdx.x;
  if (i < 40) {
    float v = 0.f;
    for (int t = 0; t < T_STEPS; ++t) {
      float yv = z[t * 40 + i];
      float nv = v + (yv - v) * 0.5f;
      float s = (nv >= 1.0f) ? 1.0f : 0.0f;
      out[t * 40 + i] = s;
      v = (nv >= 1.0f) ? 0.f : nv;
    }
  }
}

extern "C" void kernel_launch(void* const* d_in, const int* in_sizes, int n_in,
                              void* d_out, int out_size, void* d_ws, size_t ws_size,
                              hipStream_t stream) {
  const float* x = (const float*)d_in[0];
  const float* w1 = (const float*)d_in[1];
  const float* g1 = (const float*)d_in[2];
  const float* b1 = (const float*)d_in[3];
  const float* m1 = (const float*)d_in[4];
  const float* v1 = (const float*)d_in[5];
  const float* w2 = (const float*)d_in[6];
  const float* g2 = (const float*)d_in[7];
  const float* b2 = (const float*)d_in[8];
  const float* m2 = (const float*)d_in[9];
  const float* v2 = (const float*)d_in[10];
  const float* w3 = (const float*)d_in[11];
  const float* g3 = (const float*)d_in[12];
  const float* b3 = (const float*)d_in[13];
  const float* m3 = (const float*)d_in[14];
  const float* v3 = (const float*)d_in[15];
  const float* w4 = (const float*)d_in[16];
  const float* g4 = (const float*)d_in[17];
  const float* b4 = (const float*)d_in[18];
  const float* m4 = (const float*)d_in[19];
  const float* v4 = (const float*)d_in[20];
  const float* wfc = (const float*)d_in[21];
  const float* bfc = (const float*)d_in[22];
  float* out = (float*)d_out;

  float* p = (float*)d_ws;
  __hip_bfloat16* wp2 = (__hip_bfloat16*)p; p += 221184;    // 442368 bf16
  __hip_bfloat16* wp3 = (__hip_bfloat16*)p; p += 221184;
  __hip_bfloat16* wp4 = (__hip_bfloat16*)p; p += 221184;
  __hip_bfloat16* spk1 = (__hip_bfloat16*)p; p += 16777216; // 33554432 bf16 (67MB)
  float* preH = p; p += 16777216;                           // 67MB, reused all layers
  float* xp = preH;                                         // alias: consumed by layer1
                                                            // before conv32 writes preH
  __hip_bfloat16* spk2 = (__hip_bfloat16*)p; p += 4194304;  // 8388608 bf16
  float* vm2 = p; p += 2097152;
  __hip_bfloat16* spk3 = (__hip_bfloat16*)p; p += 1048576;  // 2097152 bf16
  float* vm3 = p; p += 524288;
  __hip_bfloat16* spk4 = (__hip_bfloat16*)p; p += 262144;   // 524288 bf16
  float* vm4 = p; p += 131072;
  float* z = p; p += 640;

  prep_w3_kernel<<<dim3(576, 3), 256, 0, stream>>>(w2, w3, w4, wp2, wp3, wp4);
  pad_x_kernel<<<dim3(128, 130), 192, 0, stream>>>(x, xp);

  // layer 1 in two co-halves (independent slices; identical arithmetic)
  layer1_kernel<<<dim3(16, 16, 4), 256, 0, stream>>>(xp, w1, g1, b1, m1, v1, spk1, 0);
  layer1_kernel<<<dim3(16, 16, 4), 256, 0, stream>>>(xp, w1, g1, b1, m1, v1, spk1, 64);

  // layer 2 (S=64) in two t-halves; 8x8 tiles, 2 tb per block
  conv32p_kernel<64><<<dim3(64, 1, 16), 256, 0, stream>>>(spk1, wp2, preH, 0);
  lif_pool_kernel<64><<<dim3(512, 1, 4), 256, 0, stream>>>(preH, spk2, vm2, g2, b2, m2, v2, 0, 8);
  conv32p_kernel<64><<<dim3(64, 1, 16), 256, 0, stream>>>(spk1, wp2, preH, 32);
  lif_pool_kernel<64><<<dim3(512, 1, 4), 256, 0, stream>>>(preH, spk2, vm2, g2, b2, m2, v2, 8, 8);

  // layer 3 (S=32): 16 tiles x 32 pairs
  conv32p_kernel<32><<<dim3(16, 1, 32), 256, 0, stream>>>(spk2, wp3, preH, 0);
  lif_pool_kernel<32><<<dim3(128, 1, 4), 256, 0, stream>>>(preH, spk3, vm3, g3, b3, m3, v3, 0, 16);

  // layer 4 (S=16): 4 tiles x 64 tb, single-tb
  conv32_kernel<16><<<dim3(4, 1, 64), 256, 0, stream>>>(spk3, wp4, preH, 0);
  lif_pool_kernel<16><<<dim3(32, 1, 4), 256, 0, stream>>>(preH, spk4, vm4, g4, b4, m4, v4, 0, 16);

  fc_kernel<<<64, 256, 0, stream>>>(spk4, wfc, bfc, z);
  out_lif_kernel<<<1, 64, 0, stream>>>(z, out);
}